// Round 13
// baseline (154.352 us; speedup 1.0000x reference)
//
#include <hip/hip_runtime.h>
#include <hip/hip_bf16.h>
#include <math.h>

#define NP 1024
#define R 32
#define C 16
#define GAMMA (32.0f/3.5f)
#define DC (3.5f/31.0f)
#define GDC2 (64.0f/31.0f)      // 2*GAMMA*DC (exact)
#define GDD  (112.0f/961.0f)    // GAMMA*DC*DC (exact)
#define NBANK 32   // pooled-accumulator banks (each = one 64B line)

typedef __attribute__((ext_vector_type(8))) short bf16x8;
typedef __attribute__((ext_vector_type(4))) float f32x4;
typedef __attribute__((ext_vector_type(4))) unsigned u32x4;

__device__ __forceinline__ short tobf(float x){
    __hip_bfloat16 h = __float2bfloat16(x);
    return __builtin_bit_cast(short, h);
}
// HW packed f32->bf16 (RNE). No builtin on gfx950 — inline asm. Replaces the
// ~4-VALU software RNE sequence per value with 1 instruction per pair.
__device__ __forceinline__ unsigned pack2bf(float a, float b){
    unsigned r;
    asm("v_cvt_pk_bf16_f32 %0, %1, %2" : "=v"(r) : "v"(a), "v"(b));
    return r;
}
__device__ __forceinline__ float eluf(float x){ return x > 0.f ? x : expm1f(x); }

__device__ __forceinline__ f32x4 mfma16(bf16x8 a, bf16x8 b, f32x4 c){
    return __builtin_amdgcn_mfma_f32_16x16x32_bf16(a, b, c, 0, 0, 0);
}

template<int STRIDE>
__device__ __forceinline__ void load_bfrag(const float* __restrict__ src, int q, int n,
                                           bf16x8& w){
    #pragma unroll
    for (int jj = 0; jj < 8; jj++)
        w[jj] = tobf(src[(q*8+jj)*STRIDE + n]);
}

// Gaussian-RBF via geometric recurrence (2 transcendentals instead of 8),
// packed to bf16 with 4 hardware cvt_pk (was 8 software RNE sequences).
__device__ __forceinline__ bf16x8 rbf_frag(float d, float qd8, float c0q, float c1){
    const float t0 = d - qd8;
    float r = __expf(-GAMMA * t0 * t0);
    float M = __expf(GDC2 * d) * c0q;
    float rv[8];
    rv[0] = r;
    #pragma unroll
    for (int jj = 1; jj < 8; jj++){
        r *= M;  M *= c1;
        rv[jj] = r;
    }
    u32x4 w;
    #pragma unroll
    for (int p = 0; p < 4; p++)
        w[p] = pack2bf(rv[2*p], rv[2*p+1]);
    return __builtin_bit_cast(bf16x8, w);
}

// ---------------------------------------------------------------------------
// Kernel A: layer1, half-split (2048 blocks), UNSWAPPED GEMM1 (round-10
// version — round-12 A/B showed the swapped variant is neutral-to-negative).
// W2-separable combine (7 scalars/point via atomicAdd), 2nd finisher does the
// SI transform into the interleaved xall float4 plane. Round-13 delta: afrag
// built with hardware cvt_pk (rbf_frag above).
// ---------------------------------------------------------------------------
__global__ __launch_bounds__(256) void k_l1p(
    const float* __restrict__ points,
    const float* __restrict__ W1, const float* __restrict__ B1,
    const float* __restrict__ W2, const float* __restrict__ B2,
    const float* __restrict__ si0w, const float* __restrict__ si0b,
    const float* __restrict__ si1w, const float* __restrict__ nlb,
    float* __restrict__ xall, float* __restrict__ l1c,
    unsigned* __restrict__ cntL1)
{
    __shared__ float sW[4][8];
    __shared__ float sFin[8];
    __shared__ unsigned sAm;

    const int tid  = threadIdx.x;
    const int lane = tid & 63;
    const int wv   = tid >> 6;
    const int l16  = lane & 15;
    const int q    = lane >> 4;
    const int a    = blockIdx.x >> 1;
    const int half = blockIdx.x & 1;
    const float pax = points[a*3+0], pay = points[a*3+1], paz = points[a*3+2];
    const float qd8 = (float)(q*8) * DC;
    const float c0q = __expf(-GDD * (1.0f + 16.0f*(float)q));
    const float c1  = __expf(-2.0f * GDD);

    bf16x8 w1f[2][2];
    float  b1v[2][2], w2s[2], w2t[2];
    #pragma unroll
    for (int fi = 0; fi < 2; fi++)
        #pragma unroll
        for (int nt = 0; nt < 2; nt++){
            load_bfrag<R>(W1 + fi*R*R, q, nt*16 + l16, w1f[fi][nt]);
            b1v[fi][nt] = B1[fi*R + nt*16 + l16];
        }
    #pragma unroll
    for (int nt = 0; nt < 2; nt++){
        w2s[nt] = W2[nt*16 + l16];        // filter 0 readout weights (col j)
        w2t[nt] = W2[R + nt*16 + l16];    // filter 1 readout weights
    }

    float s0a[2] = {0.f, 0.f};
    float T[2][3] = {};
    float upx = 0.f, upy = 0.f, upz = 0.f;

    for (int bt = half*8; bt < half*8 + 8; bt++){
        const int bA = bt*64 + wv*16 + l16;
        const float rx = pax - points[bA*3+0];
        const float ry = pay - points[bA*3+1];
        const float rz = paz - points[bA*3+2];
        const float ss = rx*rx + ry*ry + rz*rz;
        const float inv = 1.0f / sqrtf(fmaxf(ss, 1e-8f));
        const float dij = ss * inv;                          // == sqrt(ss), 0 on diag
        const float ux = rx*inv, uy = ry*inv, uz = rz*inv;  // ==0 on diagonal
        upx += ux; upy += uy; upz += uz;                    // 4x overcount (q dup), /4 later

        const bf16x8 afrag = rbf_frag(dij, qd8, c0q, c1);

        float uxr[4], uyr[4], uzr[4];
        #pragma unroll
        for (int r4 = 0; r4 < 4; r4++){
            const int sl = q*4 + r4;
            uxr[r4] = __shfl(ux, sl, 16);
            uyr[r4] = __shfl(uy, sl, 16);
            uzr[r4] = __shfl(uz, sl, 16);
        }

        #pragma unroll
        for (int nt = 0; nt < 2; nt++){
            f32x4 c = {b1v[0][nt], b1v[0][nt], b1v[0][nt], b1v[0][nt]};
            c = mfma16(afrag, w1f[0][nt], c);
            s0a[nt] += fmaxf(c[0],0.f)+fmaxf(c[1],0.f)+fmaxf(c[2],0.f)+fmaxf(c[3],0.f);
        }
        #pragma unroll
        for (int nt = 0; nt < 2; nt++){
            f32x4 c = {b1v[1][nt], b1v[1][nt], b1v[1][nt], b1v[1][nt]};
            c = mfma16(afrag, w1f[1][nt], c);
            #pragma unroll
            for (int r4 = 0; r4 < 4; r4++){
                const float h = fmaxf(c[r4], 0.f);
                T[nt][0] = fmaf(h, uxr[r4], T[nt][0]);
                T[nt][1] = fmaf(h, uyr[r4], T[nt][1]);
                T[nt][2] = fmaf(h, uzr[r4], T[nt][2]);
            }
        }
    }

    // per-lane W2 dot (col j = nt*16+l16 is lane-constant across quads), then
    // full-64-lane reduce of the 7 scalars: sums over rows (q) AND cols (l16).
    float v[7];
    v[0] = s0a[0]*w2s[0] + s0a[1]*w2s[1];
    #pragma unroll
    for (int i = 0; i < 3; i++)
        v[1+i] = T[0][i]*w2t[0] + T[1][i]*w2t[1];
    v[4] = upx; v[5] = upy; v[6] = upz;
    #pragma unroll
    for (int off = 32; off > 0; off >>= 1)
        #pragma unroll
        for (int k = 0; k < 7; k++)
            v[k] += __shfl_down(v[k], off, 64);
    if (lane == 0)
        #pragma unroll
        for (int k = 0; k < 7; k++) sW[wv][k] = v[k];
    __syncthreads();
    if (tid < 7)
        atomicAdd(&l1c[a*8 + tid], sW[0][tid] + sW[1][tid] + sW[2][tid] + sW[3][tid]);
    __syncthreads();                 // drain this block's atomics before counter
    if (tid == 0)
        sAm = (atomicAdd(&cntL1[a], 1u) == 1u) ? 1u : 0u;   // 2nd of the pair
    __syncthreads();
    if (sAm){
        if (tid < 7)
            sFin[tid] = __hip_atomic_load(&l1c[a*8 + tid], __ATOMIC_RELAXED,
                                          __HIP_MEMORY_SCOPE_AGENT);
        __syncthreads();
        if (tid < C){
            const int g = tid;
            const float o0  = sFin[0] + (float)NP * B2[0];
            const float o1x = sFin[1] + B2[1] * 0.25f * sFin[4];
            const float o1y = sFin[2] + B2[1] * 0.25f * sFin[5];
            const float o1z = sFin[3] + B2[1] * 0.25f * sFin[6];
            const float x0 = eluf(fmaf(o0, si0w[g], si0b[g]));
            const float w = si1w[g];
            const float tx = o1x*w, ty = o1y*w, tz = o1z*w;
            const float n = sqrtf(fmaxf(tx*tx + ty*ty + tz*tz, 1e-8f));
            const float sc = eluf(n + nlb[g]) / n;
            f32x4 st = {x0, tx*sc, ty*sc, tz*sc};
            *(f32x4*)&xall[(a*C + g)*4] = st;
        }
    }
}

// ---------------------------------------------------------------------------
// Kernel B: layer2 (filters 0/2) + readout + pool + FC — round-10 structure
// (unswapped GEMMs, shuffle-prefetched u, early float4 xall loads, wave-
// private LDS transpose, atomic combine tails). Round-13 delta: rbf_frag and
// the H-pack use hardware v_cvt_pk_bf16_f32 (1 inst/pair vs ~4 VALU/value).
// ---------------------------------------------------------------------------
__global__ __launch_bounds__(256) void k_l2r(
    const float* __restrict__ points,
    const float* __restrict__ W1, const float* __restrict__ B1,
    const float* __restrict__ W2, const float* __restrict__ B2,
    const float* __restrict__ xall,
    const float* __restrict__ si0w, const float* __restrict__ si0b,
    const float* __restrict__ fcw, const float* __restrict__ fcb,
    float* __restrict__ c00g, float* __restrict__ c10g,
    unsigned* __restrict__ cntA,
    float* __restrict__ partial, unsigned* __restrict__ cnt,
    float* __restrict__ out)
{
    __shared__ __align__(16) short sH[4][2][16*40];   // [wave][filter][row*40]
    __shared__ float sRed[4][2][16];
    __shared__ float sP[16];
    __shared__ unsigned aDone, amLast;

    const int tid  = threadIdx.x;
    const int lane = tid & 63;
    const int wv   = tid >> 6;
    const int l16  = lane & 15;
    const int q    = lane >> 4;
    const int a    = blockIdx.x >> 1;
    const int half = blockIdx.x & 1;
    const float pax = points[a*3+0], pay = points[a*3+1], paz = points[a*3+2];
    const float qd8 = (float)(q*8) * DC;
    const float c0q = __expf(-GDD * (1.0f + 16.0f*(float)q));
    const float c1  = __expf(-2.0f * GDD);

    bf16x8 w1f[2][2], w2f[2];
    float  b1v[2][2], b2v[2];
    #pragma unroll
    for (int fi = 0; fi < 2; fi++){
        const int fx = (fi == 0) ? 0 : 2;
        #pragma unroll
        for (int nt = 0; nt < 2; nt++){
            load_bfrag<R>(W1 + fx*R*R, q, 2*l16 + nt, w1f[fi][nt]);
            b1v[fi][nt] = B1[fx*R + 2*l16 + nt];
        }
        load_bfrag<C>(W2 + fx*R*C, q, l16, w2f[fi]);
        b2v[fi] = B2[fx*C + l16];
    }

    float acc0 = 0.f, acc1 = 0.f;
    short* sH0 = sH[wv][0];
    short* sH1 = sH[wv][1];

    for (int bt = half*8; bt < half*8 + 8; bt++){
        const int bA = bt*64 + wv*16 + l16;
        const float rx = pax - points[bA*3+0];
        const float ry = pay - points[bA*3+1];
        const float rz = paz - points[bA*3+2];
        const float ss = rx*rx + ry*ry + rz*rz;
        const float inv = 1.0f / sqrtf(fmaxf(ss, 1e-8f));
        const float dij = ss * inv;                          // == sqrt(ss), 0 on diag
        const float ux = rx*inv, uy = ry*inv, uz = rz*inv;  // ==0 on diagonal

        float uxr[4], uyr[4], uzr[4];
        #pragma unroll
        for (int r4 = 0; r4 < 4; r4++){
            const int sl = q*4 + r4;
            uxr[r4] = __shfl(ux, sl, 16);
            uyr[r4] = __shfl(uy, sl, 16);
            uzr[r4] = __shfl(uz, sl, 16);
        }

        // epilogue inputs issued EARLY, one float4 per row (b, f=l16)
        const f32x4* xp = (const f32x4*)&xall[((bt*64 + wv*16 + q*4)*C + l16)*4];
        float x0v[4], udv[4];
        #pragma unroll
        for (int r4 = 0; r4 < 4; r4++){
            const f32x4 xv = xp[r4*C];
            x0v[r4] = xv[0];
            udv[r4] = uxr[r4]*xv[1] + uyr[r4]*xv[2] + uzr[r4]*xv[3];
        }

        const bf16x8 afrag = rbf_frag(dij, qd8, c0q, c1);

        // GEMM1 both filters -> packed bf16 H into wave-private LDS
        #pragma unroll
        for (int fi = 0; fi < 2; fi++){
            f32x4 c0 = {b1v[fi][0], b1v[fi][0], b1v[fi][0], b1v[fi][0]};
            c0 = mfma16(afrag, w1f[fi][0], c0);
            f32x4 c1f = {b1v[fi][1], b1v[fi][1], b1v[fi][1], b1v[fi][1]};
            c1f = mfma16(afrag, w1f[fi][1], c1f);
            short* sHf = (fi == 0) ? sH0 : sH1;
            #pragma unroll
            for (int r4 = 0; r4 < 4; r4++){
                const unsigned p = pack2bf(fmaxf(c0[r4], 0.f), fmaxf(c1f[r4], 0.f));
                *(unsigned*)&sHf[(q*4+r4)*40 + 2*l16] = p;   // j=2*l16 (lo), 2*l16+1 (hi)
            }
        }
        asm volatile("s_waitcnt lgkmcnt(0)" ::: "memory");   // wave-internal transpose

        // GEMM2 filter 0 + x0 epilogue
        {
            const bf16x8 hf = *(const bf16x8*)(sH0 + l16*40 + q*8);
            f32x4 d = {0.f, 0.f, 0.f, 0.f};
            d = mfma16(hf, w2f[0], d);
            #pragma unroll
            for (int r4 = 0; r4 < 4; r4++)
                acc0 = fmaf(d[r4] + b2v[0], x0v[r4], acc0);
        }
        // GEMM2 filter 2 + u.x1 epilogue
        {
            const bf16x8 hf = *(const bf16x8*)(sH1 + l16*40 + q*8);
            f32x4 d = {0.f, 0.f, 0.f, 0.f};
            d = mfma16(hf, w2f[1], d);
            #pragma unroll
            for (int r4 = 0; r4 < 4; r4++)
                acc1 = fmaf(d[r4] + b2v[1], udv[r4], acc1);
        }
    }

    acc0 += __shfl_down(acc0, 32, 64); acc0 += __shfl_down(acc0, 16, 64);
    acc1 += __shfl_down(acc1, 32, 64); acc1 += __shfl_down(acc1, 16, 64);
    if (lane < 16){ sRed[wv][0][lane] = acc0; sRed[wv][1][lane] = acc1; }
    __syncthreads();
    // combine this half-block's partial c00/c10 into global (atomics)
    if (tid < 16)
        atomicAdd(&c00g[a*C + tid],
                  sRed[0][0][tid] + sRed[1][0][tid] + sRed[2][0][tid] + sRed[3][0][tid]);
    else if (tid < 32){
        const int f = tid - 16;
        atomicAdd(&c10g[a*C + f],
                  sRed[0][1][f] + sRed[1][1][f] + sRed[2][1][f] + sRed[3][1][f]);
    }
    __syncthreads();                 // drains this block's atomics (vmcnt)
    if (tid == 0)
        aDone = (atomicAdd(&cntA[a], 1u) == 1u) ? 1u : 0u;   // 2nd of the pair
    __syncthreads();

    if (aDone){
        // per-point readout for 'a' (both halves complete) + pooled accumulation
        if (tid < C){
            const int g = tid;
            float s = si0b[g];
            #pragma unroll
            for (int f = 0; f < C; f++){
                const float v0 = __hip_atomic_load(&c00g[a*C + f], __ATOMIC_RELAXED,
                                                   __HIP_MEMORY_SCOPE_AGENT);
                s = fmaf(v0, si0w[g*2*C + f], s);
            }
            #pragma unroll
            for (int f = 0; f < C; f++){
                const float v1 = __hip_atomic_load(&c10g[a*C + f], __ATOMIC_RELAXED,
                                                   __HIP_MEMORY_SCOPE_AGENT);
                s = fmaf(v1, si0w[g*2*C + C + f], s);
            }
            atomicAdd(&partial[(a & (NBANK-1))*C + g], eluf(s));
        }
        // two-level last-finisher-done (1024 finishers, one per 'a')
        __syncthreads();
        if (tid == 0){
            amLast = 0u;
            const unsigned p1 = atomicAdd(&cnt[a & (NBANK-1)], 1u);
            if (p1 == (NP/NBANK) - 1u){
                const unsigned p2 = atomicAdd(&cnt[NBANK], 1u);
                if (p2 == NBANK - 1u) amLast = 1u;
            }
        }
        __syncthreads();
        if (amLast){
            if (tid < C){
                float v = 0.f;
                #pragma unroll
                for (int b = 0; b < NBANK; b++)
                    v += __hip_atomic_load(&partial[b*C + tid], __ATOMIC_RELAXED,
                                           __HIP_MEMORY_SCOPE_AGENT);
                sP[tid] = v;
            }
            __syncthreads();
            if (tid < 8){
                float s = fcb[tid];
                #pragma unroll
                for (int g = 0; g < C; g++)
                    s = fmaf(sP[g] * (1.0f / (float)NP), fcw[g*8 + tid], s);
                out[tid] = s;
            }
        }
    }
}

extern "C" void kernel_launch(void* const* d_in, const int* in_sizes, int n_in,
                              void* d_out, int out_size, void* d_ws, size_t ws_size,
                              hipStream_t stream)
{
    (void)in_sizes; (void)n_in; (void)out_size; (void)ws_size;
    const float* points   = (const float*)d_in[0];
    const float* l1_W1    = (const float*)d_in[1];
    const float* l1_B1    = (const float*)d_in[2];
    const float* l1_W2    = (const float*)d_in[3];
    const float* l1_B2    = (const float*)d_in[4];
    const float* l1_si0_w = (const float*)d_in[5];
    const float* l1_si0_b = (const float*)d_in[6];
    const float* l1_si1_w = (const float*)d_in[7];
    const float* l1_nl_b  = (const float*)d_in[8];
    const float* l2_W1    = (const float*)d_in[9];
    const float* l2_B1    = (const float*)d_in[10];
    const float* l2_W2    = (const float*)d_in[11];
    const float* l2_B2    = (const float*)d_in[12];
    const float* l2_si0_w = (const float*)d_in[13];
    const float* l2_si0_b = (const float*)d_in[14];
    // d_in[15] l2_si1_w, d_in[16] l2_nl_b: dead code in the reference readout
    const float* fc_w     = (const float*)d_in[17];
    const float* fc_b     = (const float*)d_in[18];

    // ws layout: [zeroed region | xall]. Zeroed region is one contiguous
    // hipMemsetAsync (all counters + atomic-combine accumulators).
    float* ws        = (float*)d_ws;
    float* partial   = ws;                         // NBANK*C = 512 f
    unsigned* cnt    = (unsigned*)(partial + NBANK*C);  // 64 u32 (33 used)
    unsigned* cntA   = cnt + 64;                   // NP
    unsigned* cntL1  = cntA + NP;                  // NP
    float* l1c       = (float*)(cntL1 + NP);       // NP*8
    float* c00g      = l1c + NP*8;                 // NP*C
    float* c10g      = c00g + NP*C;                // NP*C
    float* xall      = c10g + NP*C;                // NP*C*4 (float4/point-chan)
    const size_t zeroBytes = (size_t)((char*)xall - (char*)ws);

    hipMemsetAsync(ws, 0, zeroBytes, stream);
    k_l1p<<<2*NP, 256, 0, stream>>>(points, l1_W1, l1_B1, l1_W2, l1_B2,
                                    l1_si0_w, l1_si0_b, l1_si1_w, l1_nl_b,
                                    xall, l1c, cntL1);
    k_l2r<<<2*NP, 256, 0, stream>>>(points, l2_W1, l2_B1, l2_W2, l2_B2,
                                    xall, l2_si0_w, l2_si0_b,
                                    fc_w, fc_b, c00g, c10g, cntA,
                                    partial, cnt, (float*)d_out);
}

// Round 14
// 143.336 us; speedup vs baseline: 1.0769x; 1.0769x over previous
//
#include <hip/hip_runtime.h>
#include <hip/hip_bf16.h>
#include <math.h>

#define NP 1024
#define R 32
#define C 16
#define GAMMA (32.0f/3.5f)
#define DC (3.5f/31.0f)
#define GDC2 (64.0f/31.0f)      // 2*GAMMA*DC (exact)
#define GDD  (112.0f/961.0f)    // GAMMA*DC*DC (exact)
#define NBANK 32   // pooled-accumulator banks (each = one 64B line)

typedef __attribute__((ext_vector_type(8))) short bf16x8;
typedef __attribute__((ext_vector_type(4))) float f32x4;

__device__ __forceinline__ short tobf(float x){
    __hip_bfloat16 h = __float2bfloat16(x);
    return __builtin_bit_cast(short, h);
}
// NOTE round-13 lesson (matches learn_hip m240): do NOT hand-write
// v_cvt_pk_bf16_f32 inline asm here — the compiler's scalar RNE sequence
// schedules better around the MFMAs (hand asm measured -11% on this kernel).
__device__ __forceinline__ unsigned pack2bf(float a, float b){
    const unsigned lo = (unsigned short)tobf(a);
    const unsigned hi = (unsigned short)tobf(b);
    return lo | (hi << 16);
}
__device__ __forceinline__ float eluf(float x){ return x > 0.f ? x : expm1f(x); }

__device__ __forceinline__ f32x4 mfma16(bf16x8 a, bf16x8 b, f32x4 c){
    return __builtin_amdgcn_mfma_f32_16x16x32_bf16(a, b, c, 0, 0, 0);
}

template<int STRIDE>
__device__ __forceinline__ void load_bfrag(const float* __restrict__ src, int q, int n,
                                           bf16x8& w){
    #pragma unroll
    for (int jj = 0; jj < 8; jj++)
        w[jj] = tobf(src[(q*8+jj)*STRIDE + n]);
}

// Gaussian-RBF via geometric recurrence (2 transcendentals instead of 8).
__device__ __forceinline__ bf16x8 rbf_frag(float d, float qd8, float c0q, float c1){
    const float t0 = d - qd8;
    float r = __expf(-GAMMA * t0 * t0);
    float M = __expf(GDC2 * d) * c0q;
    bf16x8 afrag;
    afrag[0] = tobf(r);
    #pragma unroll
    for (int jj = 1; jj < 8; jj++){
        r *= M;  M *= c1;
        afrag[jj] = tobf(r);
    }
    return afrag;
}

// ---------------------------------------------------------------------------
// Kernel A: layer1, half-split (2048 blocks = 2 per point, 8 b-tiles each),
// W2-separable combine (7 scalars/point via atomicAdd), 2nd finisher does the
// SI transform into the interleaved xall float4 plane {x0, x1x, x1y, x1z}.
// rbf recurrence (2 exps) + dij = ss*inv (no sqrt): 3 trans ops per iter.
// ROUND-10 VERSION — verified session best (144.3 us). Swapped-GEMM variant
// (r11/r12) and hw-cvt_pk variant (r13) both measured worse and are reverted.
// ---------------------------------------------------------------------------
__global__ __launch_bounds__(256) void k_l1p(
    const float* __restrict__ points,
    const float* __restrict__ W1, const float* __restrict__ B1,
    const float* __restrict__ W2, const float* __restrict__ B2,
    const float* __restrict__ si0w, const float* __restrict__ si0b,
    const float* __restrict__ si1w, const float* __restrict__ nlb,
    float* __restrict__ xall, float* __restrict__ l1c,
    unsigned* __restrict__ cntL1)
{
    __shared__ float sW[4][8];
    __shared__ float sFin[8];
    __shared__ unsigned sAm;

    const int tid  = threadIdx.x;
    const int lane = tid & 63;
    const int wv   = tid >> 6;
    const int l16  = lane & 15;
    const int q    = lane >> 4;
    const int a    = blockIdx.x >> 1;
    const int half = blockIdx.x & 1;
    const float pax = points[a*3+0], pay = points[a*3+1], paz = points[a*3+2];
    const float qd8 = (float)(q*8) * DC;
    const float c0q = __expf(-GDD * (1.0f + 16.0f*(float)q));
    const float c1  = __expf(-2.0f * GDD);

    bf16x8 w1f[2][2];
    float  b1v[2][2], w2s[2], w2t[2];
    #pragma unroll
    for (int fi = 0; fi < 2; fi++)
        #pragma unroll
        for (int nt = 0; nt < 2; nt++){
            load_bfrag<R>(W1 + fi*R*R, q, nt*16 + l16, w1f[fi][nt]);
            b1v[fi][nt] = B1[fi*R + nt*16 + l16];
        }
    #pragma unroll
    for (int nt = 0; nt < 2; nt++){
        w2s[nt] = W2[nt*16 + l16];        // filter 0 readout weights (col j)
        w2t[nt] = W2[R + nt*16 + l16];    // filter 1 readout weights
    }

    float s0a[2] = {0.f, 0.f};
    float T[2][3] = {};
    float upx = 0.f, upy = 0.f, upz = 0.f;

    for (int bt = half*8; bt < half*8 + 8; bt++){
        const int bA = bt*64 + wv*16 + l16;
        const float rx = pax - points[bA*3+0];
        const float ry = pay - points[bA*3+1];
        const float rz = paz - points[bA*3+2];
        const float ss = rx*rx + ry*ry + rz*rz;
        const float inv = 1.0f / sqrtf(fmaxf(ss, 1e-8f));
        const float dij = ss * inv;                          // == sqrt(ss), 0 on diag
        const float ux = rx*inv, uy = ry*inv, uz = rz*inv;  // ==0 on diagonal
        upx += ux; upy += uy; upz += uz;                    // 4x overcount (q dup), /4 later

        const bf16x8 afrag = rbf_frag(dij, qd8, c0q, c1);

        float uxr[4], uyr[4], uzr[4];
        #pragma unroll
        for (int r4 = 0; r4 < 4; r4++){
            const int sl = q*4 + r4;
            uxr[r4] = __shfl(ux, sl, 16);
            uyr[r4] = __shfl(uy, sl, 16);
            uzr[r4] = __shfl(uz, sl, 16);
        }

        #pragma unroll
        for (int nt = 0; nt < 2; nt++){
            f32x4 c = {b1v[0][nt], b1v[0][nt], b1v[0][nt], b1v[0][nt]};
            c = mfma16(afrag, w1f[0][nt], c);
            s0a[nt] += fmaxf(c[0],0.f)+fmaxf(c[1],0.f)+fmaxf(c[2],0.f)+fmaxf(c[3],0.f);
        }
        #pragma unroll
        for (int nt = 0; nt < 2; nt++){
            f32x4 c = {b1v[1][nt], b1v[1][nt], b1v[1][nt], b1v[1][nt]};
            c = mfma16(afrag, w1f[1][nt], c);
            #pragma unroll
            for (int r4 = 0; r4 < 4; r4++){
                const float h = fmaxf(c[r4], 0.f);
                T[nt][0] = fmaf(h, uxr[r4], T[nt][0]);
                T[nt][1] = fmaf(h, uyr[r4], T[nt][1]);
                T[nt][2] = fmaf(h, uzr[r4], T[nt][2]);
            }
        }
    }

    // per-lane W2 dot (col j = nt*16+l16 is lane-constant across quads), then
    // full-64-lane reduce of the 7 scalars: sums over rows (q) AND cols (l16).
    float v[7];
    v[0] = s0a[0]*w2s[0] + s0a[1]*w2s[1];
    #pragma unroll
    for (int i = 0; i < 3; i++)
        v[1+i] = T[0][i]*w2t[0] + T[1][i]*w2t[1];
    v[4] = upx; v[5] = upy; v[6] = upz;
    #pragma unroll
    for (int off = 32; off > 0; off >>= 1)
        #pragma unroll
        for (int k = 0; k < 7; k++)
            v[k] += __shfl_down(v[k], off, 64);
    if (lane == 0)
        #pragma unroll
        for (int k = 0; k < 7; k++) sW[wv][k] = v[k];
    __syncthreads();
    if (tid < 7)
        atomicAdd(&l1c[a*8 + tid], sW[0][tid] + sW[1][tid] + sW[2][tid] + sW[3][tid]);
    __syncthreads();                 // drain this block's atomics before counter
    if (tid == 0)
        sAm = (atomicAdd(&cntL1[a], 1u) == 1u) ? 1u : 0u;   // 2nd of the pair
    __syncthreads();
    if (sAm){
        if (tid < 7)
            sFin[tid] = __hip_atomic_load(&l1c[a*8 + tid], __ATOMIC_RELAXED,
                                          __HIP_MEMORY_SCOPE_AGENT);
        __syncthreads();
        if (tid < C){
            const int g = tid;
            const float o0  = sFin[0] + (float)NP * B2[0];
            const float o1x = sFin[1] + B2[1] * 0.25f * sFin[4];
            const float o1y = sFin[2] + B2[1] * 0.25f * sFin[5];
            const float o1z = sFin[3] + B2[1] * 0.25f * sFin[6];
            const float x0 = eluf(fmaf(o0, si0w[g], si0b[g]));
            const float w = si1w[g];
            const float tx = o1x*w, ty = o1y*w, tz = o1z*w;
            const float n = sqrtf(fmaxf(tx*tx + ty*ty + tz*tz, 1e-8f));
            const float sc = eluf(n + nlb[g]) / n;
            f32x4 st = {x0, tx*sc, ty*sc, tz*sc};
            *(f32x4*)&xall[(a*C + g)*4] = st;
        }
    }
}

// ---------------------------------------------------------------------------
// Kernel B: layer2 (filters 0/2) + per-point readout + mean-pool + final FC.
// ROUND-10 VERSION — verified session best. 2048-block half-split, unforced
// bounds (VGPR 60, spill-free), shuffle-prefetched u, EARLY float4 xall
// loads, rbf recurrence, wave-private LDS transpose, atomic combine tails.
// ---------------------------------------------------------------------------
__global__ __launch_bounds__(256) void k_l2r(
    const float* __restrict__ points,
    const float* __restrict__ W1, const float* __restrict__ B1,
    const float* __restrict__ W2, const float* __restrict__ B2,
    const float* __restrict__ xall,
    const float* __restrict__ si0w, const float* __restrict__ si0b,
    const float* __restrict__ fcw, const float* __restrict__ fcb,
    float* __restrict__ c00g, float* __restrict__ c10g,
    unsigned* __restrict__ cntA,
    float* __restrict__ partial, unsigned* __restrict__ cnt,
    float* __restrict__ out)
{
    __shared__ __align__(16) short sH[4][2][16*40];   // [wave][filter][row*40]
    __shared__ float sRed[4][2][16];
    __shared__ float sP[16];
    __shared__ unsigned aDone, amLast;

    const int tid  = threadIdx.x;
    const int lane = tid & 63;
    const int wv   = tid >> 6;
    const int l16  = lane & 15;
    const int q    = lane >> 4;
    const int a    = blockIdx.x >> 1;
    const int half = blockIdx.x & 1;
    const float pax = points[a*3+0], pay = points[a*3+1], paz = points[a*3+2];
    const float qd8 = (float)(q*8) * DC;
    const float c0q = __expf(-GDD * (1.0f + 16.0f*(float)q));
    const float c1  = __expf(-2.0f * GDD);

    bf16x8 w1f[2][2], w2f[2];
    float  b1v[2][2], b2v[2];
    #pragma unroll
    for (int fi = 0; fi < 2; fi++){
        const int fx = (fi == 0) ? 0 : 2;
        #pragma unroll
        for (int nt = 0; nt < 2; nt++){
            load_bfrag<R>(W1 + fx*R*R, q, 2*l16 + nt, w1f[fi][nt]);
            b1v[fi][nt] = B1[fx*R + 2*l16 + nt];
        }
        load_bfrag<C>(W2 + fx*R*C, q, l16, w2f[fi]);
        b2v[fi] = B2[fx*C + l16];
    }

    float acc0 = 0.f, acc1 = 0.f;
    short* sH0 = sH[wv][0];
    short* sH1 = sH[wv][1];

    for (int bt = half*8; bt < half*8 + 8; bt++){
        const int bA = bt*64 + wv*16 + l16;
        const float rx = pax - points[bA*3+0];
        const float ry = pay - points[bA*3+1];
        const float rz = paz - points[bA*3+2];
        const float ss = rx*rx + ry*ry + rz*rz;
        const float inv = 1.0f / sqrtf(fmaxf(ss, 1e-8f));
        const float dij = ss * inv;                          // == sqrt(ss), 0 on diag
        const float ux = rx*inv, uy = ry*inv, uz = rz*inv;  // ==0 on diagonal

        float uxr[4], uyr[4], uzr[4];
        #pragma unroll
        for (int r4 = 0; r4 < 4; r4++){
            const int sl = q*4 + r4;
            uxr[r4] = __shfl(ux, sl, 16);
            uyr[r4] = __shfl(uy, sl, 16);
            uzr[r4] = __shfl(uz, sl, 16);
        }

        // epilogue inputs issued EARLY, one float4 per row (b, f=l16)
        const f32x4* xp = (const f32x4*)&xall[((bt*64 + wv*16 + q*4)*C + l16)*4];
        float x0v[4], udv[4];
        #pragma unroll
        for (int r4 = 0; r4 < 4; r4++){
            const f32x4 xv = xp[r4*C];
            x0v[r4] = xv[0];
            udv[r4] = uxr[r4]*xv[1] + uyr[r4]*xv[2] + uzr[r4]*xv[3];
        }

        const bf16x8 afrag = rbf_frag(dij, qd8, c0q, c1);

        // GEMM1 both filters -> packed bf16 H into wave-private LDS
        #pragma unroll
        for (int fi = 0; fi < 2; fi++){
            f32x4 c0 = {b1v[fi][0], b1v[fi][0], b1v[fi][0], b1v[fi][0]};
            c0 = mfma16(afrag, w1f[fi][0], c0);
            f32x4 c1f = {b1v[fi][1], b1v[fi][1], b1v[fi][1], b1v[fi][1]};
            c1f = mfma16(afrag, w1f[fi][1], c1f);
            short* sHf = (fi == 0) ? sH0 : sH1;
            #pragma unroll
            for (int r4 = 0; r4 < 4; r4++){
                const unsigned p = pack2bf(fmaxf(c0[r4], 0.f), fmaxf(c1f[r4], 0.f));
                *(unsigned*)&sHf[(q*4+r4)*40 + 2*l16] = p;   // j=2*l16 (lo), 2*l16+1 (hi)
            }
        }
        asm volatile("s_waitcnt lgkmcnt(0)" ::: "memory");   // wave-internal transpose

        // GEMM2 filter 0 + x0 epilogue
        {
            const bf16x8 hf = *(const bf16x8*)(sH0 + l16*40 + q*8);
            f32x4 d = {0.f, 0.f, 0.f, 0.f};
            d = mfma16(hf, w2f[0], d);
            #pragma unroll
            for (int r4 = 0; r4 < 4; r4++)
                acc0 = fmaf(d[r4] + b2v[0], x0v[r4], acc0);
        }
        // GEMM2 filter 2 + u.x1 epilogue
        {
            const bf16x8 hf = *(const bf16x8*)(sH1 + l16*40 + q*8);
            f32x4 d = {0.f, 0.f, 0.f, 0.f};
            d = mfma16(hf, w2f[1], d);
            #pragma unroll
            for (int r4 = 0; r4 < 4; r4++)
                acc1 = fmaf(d[r4] + b2v[1], udv[r4], acc1);
        }
    }

    acc0 += __shfl_down(acc0, 32, 64); acc0 += __shfl_down(acc0, 16, 64);
    acc1 += __shfl_down(acc1, 32, 64); acc1 += __shfl_down(acc1, 16, 64);
    if (lane < 16){ sRed[wv][0][lane] = acc0; sRed[wv][1][lane] = acc1; }
    __syncthreads();
    // combine this half-block's partial c00/c10 into global (atomics)
    if (tid < 16)
        atomicAdd(&c00g[a*C + tid],
                  sRed[0][0][tid] + sRed[1][0][tid] + sRed[2][0][tid] + sRed[3][0][tid]);
    else if (tid < 32){
        const int f = tid - 16;
        atomicAdd(&c10g[a*C + f],
                  sRed[0][1][f] + sRed[1][1][f] + sRed[2][1][f] + sRed[3][1][f]);
    }
    __syncthreads();                 // drains this block's atomics (vmcnt)
    if (tid == 0)
        aDone = (atomicAdd(&cntA[a], 1u) == 1u) ? 1u : 0u;   // 2nd of the pair
    __syncthreads();

    if (aDone){
        // per-point readout for 'a' (both halves complete) + pooled accumulation
        if (tid < C){
            const int g = tid;
            float s = si0b[g];
            #pragma unroll
            for (int f = 0; f < C; f++){
                const float v0 = __hip_atomic_load(&c00g[a*C + f], __ATOMIC_RELAXED,
                                                   __HIP_MEMORY_SCOPE_AGENT);
                s = fmaf(v0, si0w[g*2*C + f], s);
            }
            #pragma unroll
            for (int f = 0; f < C; f++){
                const float v1 = __hip_atomic_load(&c10g[a*C + f], __ATOMIC_RELAXED,
                                                   __HIP_MEMORY_SCOPE_AGENT);
                s = fmaf(v1, si0w[g*2*C + C + f], s);
            }
            atomicAdd(&partial[(a & (NBANK-1))*C + g], eluf(s));
        }
        // two-level last-finisher-done (1024 finishers, one per 'a')
        __syncthreads();
        if (tid == 0){
            amLast = 0u;
            const unsigned p1 = atomicAdd(&cnt[a & (NBANK-1)], 1u);
            if (p1 == (NP/NBANK) - 1u){
                const unsigned p2 = atomicAdd(&cnt[NBANK], 1u);
                if (p2 == NBANK - 1u) amLast = 1u;
            }
        }
        __syncthreads();
        if (amLast){
            if (tid < C){
                float v = 0.f;
                #pragma unroll
                for (int b = 0; b < NBANK; b++)
                    v += __hip_atomic_load(&partial[b*C + tid], __ATOMIC_RELAXED,
                                           __HIP_MEMORY_SCOPE_AGENT);
                sP[tid] = v;
            }
            __syncthreads();
            if (tid < 8){
                float s = fcb[tid];
                #pragma unroll
                for (int g = 0; g < C; g++)
                    s = fmaf(sP[g] * (1.0f / (float)NP), fcw[g*8 + tid], s);
                out[tid] = s;
            }
        }
    }
}

extern "C" void kernel_launch(void* const* d_in, const int* in_sizes, int n_in,
                              void* d_out, int out_size, void* d_ws, size_t ws_size,
                              hipStream_t stream)
{
    (void)in_sizes; (void)n_in; (void)out_size; (void)ws_size;
    const float* points   = (const float*)d_in[0];
    const float* l1_W1    = (const float*)d_in[1];
    const float* l1_B1    = (const float*)d_in[2];
    const float* l1_W2    = (const float*)d_in[3];
    const float* l1_B2    = (const float*)d_in[4];
    const float* l1_si0_w = (const float*)d_in[5];
    const float* l1_si0_b = (const float*)d_in[6];
    const float* l1_si1_w = (const float*)d_in[7];
    const float* l1_nl_b  = (const float*)d_in[8];
    const float* l2_W1    = (const float*)d_in[9];
    const float* l2_B1    = (const float*)d_in[10];
    const float* l2_W2    = (const float*)d_in[11];
    const float* l2_B2    = (const float*)d_in[12];
    const float* l2_si0_w = (const float*)d_in[13];
    const float* l2_si0_b = (const float*)d_in[14];
    // d_in[15] l2_si1_w, d_in[16] l2_nl_b: dead code in the reference readout
    const float* fc_w     = (const float*)d_in[17];
    const float* fc_b     = (const float*)d_in[18];

    // ws layout: [zeroed region | xall]. Zeroed region is one contiguous
    // hipMemsetAsync (all counters + atomic-combine accumulators).
    float* ws        = (float*)d_ws;
    float* partial   = ws;                         // NBANK*C = 512 f
    unsigned* cnt    = (unsigned*)(partial + NBANK*C);  // 64 u32 (33 used)
    unsigned* cntA   = cnt + 64;                   // NP
    unsigned* cntL1  = cntA + NP;                  // NP
    float* l1c       = (float*)(cntL1 + NP);       // NP*8
    float* c00g      = l1c + NP*8;                 // NP*C
    float* c10g      = c00g + NP*C;                // NP*C
    float* xall      = c10g + NP*C;                // NP*C*4 (float4/point-chan)
    const size_t zeroBytes = (size_t)((char*)xall - (char*)ws);

    hipMemsetAsync(ws, 0, zeroBytes, stream);
    k_l1p<<<2*NP, 256, 0, stream>>>(points, l1_W1, l1_B1, l1_W2, l1_B2,
                                    l1_si0_w, l1_si0_b, l1_si1_w, l1_nl_b,
                                    xall, l1c, cntL1);
    k_l2r<<<2*NP, 256, 0, stream>>>(points, l2_W1, l2_B1, l2_W2, l2_B2,
                                    xall, l2_si0_w, l2_si0_b,
                                    fc_w, fc_b, c00g, c10g, cntA,
                                    partial, cnt, (float*)d_out);
}